// Round 5
// baseline (396.183 us; speedup 1.0000x reference)
//
#include <hip/hip_runtime.h>
#include <cstddef>

#define PI_F 3.14159265358979323846f
#define A_  5
#define C_  12
#define RPG (C_ * A_)    // (coil,a) planes = 60

// ---------------------------------------------------------------------------
// Pipeline R5: every global READ coalesced; transpose-scatter moved to the
// WRITE side (stores are fire-and-forget; scattered loads stall the wave --
// R4's colfmc 122->166us regression was scattered bufA loads).
//   k_inT   : transpose x (5) + mps (12) -> g_xT/g_mT [.][x][y]      (coalesced r/w)
//   k_fft1c : mpsT*xT, pad y, FFT along y; SCATTER-write g_bufA[ca][ky][x]
//   k_colfmc: per (coil,ky): COALESCED read bufA rows (prefetched), pad x,
//             5 fwd x-FFTs, mix with kern[m][ky][kx] native (coalesced),
//             5 inv x-FFTs, crop x; SCATTER-write g_bufB[ca][x][ky]
//   k_outfr : per (a,x): COALESCED read bufB rows (prefetched), 12 coil
//             ky-IFFTs, crop y, conj(mpsT) reduce; SCATTER-write planar out
// ca = coil*A_ + a.  k_outT/g_oT deleted.  HBM total ~330 MB.
// ---------------------------------------------------------------------------
__device__ float2 g_bufA[RPG * 512 * 256];  //  63 MB  [ca][ky][x]
__device__ float2 g_bufB[RPG * 256 * 512];  //  63 MB  [ca][x][ky]
__device__ float2 g_xT[5  * 65536];         // 2.5 MB  [a][x][y]
__device__ float2 g_mT[12 * 65536];         // 6 MB    [c][x][y]

// ---------------------------------------------------------------------------
// SoA LDS FFT. Pad P(i)=i+(i>>3) everywhere (data + tab): R4's 8.9M
// conflicts were the Ns=4/Ns=16 STORE clusters (idxD groups 16g+0..3 ->
// 4-way under i>>5 padding). With i>>3: group starts 18g mod 32 are all
// distinct -> stores exactly 2-way (free); loads ~2-3-way. Net win.
// ---------------------------------------------------------------------------
#define NP 576
__device__ inline int P(int i) { return i + (i >> 3); }

__device__ inline void build_tab(float2* tab, int t) {
    #pragma unroll
    for (int q = 0; q < 2; ++q) {
        int k = t + q * 128;                 // k in [0,256)
        float s, c;
        __sincosf(-2.0f * PI_F * (float)k * (1.0f / 512.0f), &s, &c);
        tab[P(k)] = make_float2(c, s);
    }
}

template<int DIR>
__device__ inline float2 cmulw(float2 v, float2 w) {
    float cv = w.x, sv = (DIR < 0) ? w.y : -w.y;   // DIR=+1 -> conj(w)
    return make_float2(v.x * cv - v.y * sv, v.x * sv + v.y * cv);
}

// 512-pt FFT, 128 threads: 4 radix-4 stages + 1 radix-2 stage.
// Input in (Ar,Ai), result lands in (Br,Bi); both are scratch (ping-pong
// A->B->A->B->A, r2: A->B). Head barrier each stage; ends with barrier.
template<int DIR>
__device__ void fft512(float* Ar, float* Ai, float* Br, float* Bi,
                       const float2* tab, int t) {
    float *srcR = Ar, *srcI = Ai, *dstR = Br, *dstI = Bi;
    int Ns = 1;
    #pragma unroll
    for (int s = 0; s < 4; ++s) {
        __syncthreads();
        int j = t;
        int m = j & (Ns - 1);
        int e1 = m << (7 - 2 * s);            // e1 in [0,128)
        float2 w1 = tab[P(e1)], w2 = tab[P(2 * e1)];
        float2 w3 = make_float2(w1.x * w2.x - w1.y * w2.y,
                                w1.x * w2.y + w1.y * w2.x);   // W^(3*e1)
        int i0 = P(j), i1 = P(j + 128), i2 = P(j + 256), i3 = P(j + 384);
        float2 v0 = make_float2(srcR[i0], srcI[i0]);
        float2 v1 = cmulw<DIR>(make_float2(srcR[i1], srcI[i1]), w1);
        float2 v2 = cmulw<DIR>(make_float2(srcR[i2], srcI[i2]), w2);
        float2 v3 = cmulw<DIR>(make_float2(srcR[i3], srcI[i3]), w3);
        float2 t0 = make_float2(v0.x + v2.x, v0.y + v2.y);
        float2 t1 = make_float2(v0.x - v2.x, v0.y - v2.y);
        float2 t2 = make_float2(v1.x + v3.x, v1.y + v3.y);
        float2 t3 = make_float2(v1.x - v3.x, v1.y - v3.y);
        float2 y0 = make_float2(t0.x + t2.x, t0.y + t2.y);
        float2 y2 = make_float2(t0.x - t2.x, t0.y - t2.y);
        float2 y1, y3;
        if (DIR < 0) {
            y1 = make_float2(t1.x + t3.y, t1.y - t3.x);
            y3 = make_float2(t1.x - t3.y, t1.y + t3.x);
        } else {
            y1 = make_float2(t1.x - t3.y, t1.y + t3.x);
            y3 = make_float2(t1.x + t3.y, t1.y - t3.x);
        }
        int idxD = ((j & ~(Ns - 1)) << 2) | m;
        int o0 = P(idxD), o1 = P(idxD + Ns);
        int o2 = P(idxD + 2 * Ns), o3 = P(idxD + 3 * Ns);
        dstR[o0] = y0.x; dstI[o0] = y0.y;
        dstR[o1] = y1.x; dstI[o1] = y1.y;
        dstR[o2] = y2.x; dstI[o2] = y2.y;
        dstR[o3] = y3.x; dstI[o3] = y3.y;
        float* tr = srcR; srcR = dstR; dstR = tr;
        float* ti = srcI; srcI = dstI; dstI = ti;
        Ns <<= 2;
    }
    __syncthreads();
    #pragma unroll
    for (int q = 0; q < 2; ++q) {
        int j = t + q * 128;                  // j in [0,256)
        float2 w = tab[P(j)];
        int i0 = P(j), i1 = P(j + 256);
        float2 v0 = make_float2(srcR[i0], srcI[i0]);
        float2 tw = cmulw<DIR>(make_float2(srcR[i1], srcI[i1]), w);
        dstR[i0] = v0.x + tw.x; dstI[i0] = v0.y + tw.y;
        dstR[i1] = v0.x - tw.x; dstI[i1] = v0.y - tw.y;
    }
    __syncthreads();
}

// ---------------------------------------------------------------------------
// Input transpose: x planes (z<5) and mps planes (z in [5,17)) -> [.][x][y].
// ---------------------------------------------------------------------------
__global__ void k_inT(const float* __restrict__ xr, const float* __restrict__ xi,
                      const float* __restrict__ mr, const float* __restrict__ mi) {
    __shared__ float tR[32][33], tI[32][33];
    int z = blockIdx.z;
    const float* pr; const float* pi; float2* dst;
    if (z < 5) {
        pr = xr + (size_t)z * 65536; pi = xi + (size_t)z * 65536;
        dst = g_xT + (size_t)z * 65536;
    } else {
        int c = z - 5;
        pr = mr + (size_t)c * 65536; pi = mi + (size_t)c * 65536;
        dst = g_mT + (size_t)c * 65536;
    }
    int w0 = blockIdx.x * 32, h0 = blockIdx.y * 32;
    int tx = threadIdx.x, ty = threadIdx.y;
    for (int i = ty; i < 32; i += 8) {
        size_t idx = (size_t)(h0 + i) * 256 + (w0 + tx);
        tR[i][tx] = pr[idx];
        tI[i][tx] = pi[idx];
    }
    __syncthreads();
    for (int i = ty; i < 32; i += 8)
        dst[(size_t)(w0 + i) * 256 + (h0 + tx)] =
            make_float2(tR[tx][i], tI[tx][i]);
}

// ---------------------------------------------------------------------------
// Pass 1: modulate mpsT*xT (coalesced float4 reads), pad y, FFT along y,
// SCATTER-write g_bufA[ca][ky][xcol] (stride-256-float2 stores, fire-and-
// forget). Block = ca*256 + xcol.
// ---------------------------------------------------------------------------
__global__ void k_fft1c() {
    int row = blockIdx.x;
    int ca = row >> 8;
    int xcol = row & 255;
    int coil = ca / A_;
    int a = ca - coil * A_;
    int t = threadIdx.x;
    __shared__ float Are[NP], Aim[NP], Bre[NP], Bim[NP];
    __shared__ float2 tab[288];
    build_tab(tab, t);
    const float4* xs4 = (const float4*)(g_xT + (size_t)a * 65536 + (size_t)xcol * 256);
    const float4* ms4 = (const float4*)(g_mT + (size_t)coil * 65536 + (size_t)xcol * 256);
    float4 xv = xs4[t], mv = ms4[t];     // y = 2t (xy), 2t+1 (zw)
    Are[P(t)] = 0.f;       Aim[P(t)] = 0.f;        // pad y5 < 128
    Are[P(t + 384)] = 0.f; Aim[P(t + 384)] = 0.f;  // pad y5 >= 384
    int p = P(128 + 2 * t);
    Are[p] = xv.x * mv.x - xv.y * mv.y;
    Aim[p] = xv.x * mv.y + xv.y * mv.x;
    p = P(129 + 2 * t);
    Are[p] = xv.z * mv.z - xv.w * mv.w;
    Aim[p] = xv.z * mv.w + xv.w * mv.z;
    fft512<-1>(Are, Aim, Bre, Bim, tab, t);
    float2* o = g_bufA + (size_t)ca * 131072 + xcol;   // + ky*256
    #pragma unroll
    for (int q = 0; q < 4; ++q) {
        int ky = t + q * 128;
        int pp = P(ky);
        o[(size_t)ky * 256] = make_float2(Bre[pp], Bim[pp]);
    }
}

// ---------------------------------------------------------------------------
// FUSED pass 2: per (coil,ky): 5 fwd x-FFTs + mix + 5 inv x-FFTs.
//   - bufA rows [ca][ky][0..255] read COALESCED (float4), double-buffered:
//     next ain's load issued before current ain's FFT -> latency hidden.
//   - K from native kr/ki [m][ky][kx]: lanes vary kx -> coalesced; scale
//     folded. XCD swizzle keeps the 12 coil-blocks of a ky on one XCD so
//     the K row (102 KB) is read from HBM once, reused 12x from L2.
//   - inv results SCATTER-written to bufB[ca][x][ky] (stride-512-float2
//     stores); outfr then reads coalesced.
// Swizzle: b -> xcd=b&7, s=b>>3; v=s/96, w=s%96; u=xcd+8v;
//          coil=w%12, ky=8u+w/12. Bijective.
// LDS: S 4.6K + FR/FI 23K + tab 2.3K = 29.9 KB -> 5 blocks/CU.
// ---------------------------------------------------------------------------
__global__ void __launch_bounds__(128) k_colfmc(const float* __restrict__ kr,
                                                const float* __restrict__ ki) {
    int b = blockIdx.x;
    int xcd = b & 7;
    int s = b >> 3;                  // 0..767
    int v = s / 96, w = s % 96;
    int u = xcd + (v << 3);          // ky-octet 0..63
    int coil = w % C_;
    int ky = (u << 3) + (w / C_);
    int t = threadIdx.x;
    __shared__ float Sre[NP], Sim[NP];
    __shared__ float FR[A_][NP], FI[A_][NP];
    __shared__ float2 tab[288];
    build_tab(tab, t);

    // ---- forward: 5 ain x-FFTs, coalesced loads double-buffered ----
    const float2* bA = g_bufA + ((size_t)coil * A_) * 131072 + (size_t)ky * 256;
    float4 cur = ((const float4*)bA)[t];           // ain = 0
    for (int ain = 0; ain < A_; ++ain) {
        float4 nxt = cur;
        if (ain + 1 < A_)                           // issue next load now;
            nxt = ((const float4*)(bA + (size_t)(ain + 1) * 131072))[t];
        // stage cur: x = 2t, 2t+1 -> padded x5 = x + 128
        Sre[P(t)] = 0.f;       Sim[P(t)] = 0.f;
        Sre[P(t + 384)] = 0.f; Sim[P(t + 384)] = 0.f;
        int p = P(128 + 2 * t);
        Sre[p] = cur.x; Sim[p] = cur.y;
        p = P(129 + 2 * t);
        Sre[p] = cur.z; Sim[p] = cur.w;
        fft512<-1>(Sre, Sim, FR[ain], FI[ain], tab, t);  // result -> FR/FI[ain]
        cur = nxt;
    }

    // ---- mix: G[aout] = scale * sum_ain kern[aout][ain][ky][kx] * F[ain] ----
    const float scale = 4.0f / 262144.0f;   // OVERSAMP^2 / (Hp*Wp)
    size_t kyBase = (size_t)ky << 9;
    #pragma unroll
    for (int q = 0; q < 4; ++q) {
        int kx = t + q * 128;
        float krB[25], kiB[25];
        #pragma unroll
        for (int m = 0; m < 25; ++m) {
            size_t idx = ((size_t)m << 18) + kyBase + kx;
            krB[m] = kr[idx];
            kiB[m] = ki[idx];
        }
        int p = P(kx);
        float fr[A_], fi[A_];
        #pragma unroll
        for (int ain = 0; ain < A_; ++ain) {
            fr[ain] = FR[ain][p];
            fi[ain] = FI[ain][p];
        }
        #pragma unroll
        for (int aout = 0; aout < A_; ++aout) {
            float gr = 0.f, gi = 0.f;
            #pragma unroll
            for (int ain = 0; ain < A_; ++ain) {
                float kre = krB[aout * A_ + ain], kim = kiB[aout * A_ + ain];
                gr += kre * fr[ain] - kim * fi[ain];
                gi += kre * fi[ain] + kim * fr[ain];
            }
            FR[aout][p] = scale * gr;
            FI[aout][p] = scale * gi;
        }
    }
    // per-thread kx ownership -> no barrier; next fft's head barrier covers

    // ---- inverse: 5 aout x-IFFTs, crop x, scatter-store bufB[ca][x][ky] ----
    for (int aout = 0; aout < A_; ++aout) {
        fft512<1>(FR[aout], FI[aout], Sre, Sim, tab, t);  // result -> S
        float2* oB = g_bufB + ((size_t)(coil * A_ + aout)) * 131072 + ky;
        int p0 = P(128 + 2 * t), p1 = P(129 + 2 * t);     // keep x5 in [128,384)
        oB[(size_t)(2 * t) * 512]     = make_float2(Sre[p0], Sim[p0]);
        oB[(size_t)(2 * t + 1) * 512] = make_float2(Sre[p1], Sim[p1]);
    }
}

// ---------------------------------------------------------------------------
// FUSED output: per (a,xcol): 12 coil ky-IFFTs + crop y + conj(mpsT) reduce,
// then SCATTER-write the planar output directly (k_outT deleted).
//   - bufB rows [ca][xcol][0..511] read COALESCED (float4), coil-double-
//     buffered; mpsT float4 rows likewise.
// ---------------------------------------------------------------------------
__global__ void k_outfr(float* __restrict__ out, int outFloats) {
    int b = blockIdx.x;
    int a = b >> 8;
    int xcol = b & 255;
    int t = threadIdx.x;
    __shared__ float Are[NP], Aim[NP], Bre[NP], Bim[NP];
    __shared__ float2 tab[288];
    build_tab(tab, t);
    float ar0 = 0.f, ai0 = 0.f, ar1 = 0.f, ai1 = 0.f;
    const float2* bB = g_bufB + (size_t)a * 131072 + (size_t)xcol * 512;
    const float2* mT = g_mT + (size_t)xcol * 256;
    float4 c0 = ((const float4*)bB)[t];            // coil 0, ky = 2t,2t+1
    float4 c1 = ((const float4*)bB)[t + 128];      // ky = 256+2t, 257+2t
    float4 cm = ((const float4*)mT)[t];            // mps y = 2t, 2t+1
    for (int c = 0; c < C_; ++c) {
        int p = P(2 * t);       Are[p] = c0.x; Aim[p] = c0.y;
        p = P(2 * t + 1);       Are[p] = c0.z; Aim[p] = c0.w;
        p = P(256 + 2 * t);     Are[p] = c1.x; Aim[p] = c1.y;
        p = P(257 + 2 * t);     Are[p] = c1.z; Aim[p] = c1.w;
        float4 n0 = c0, n1 = c1, nm = cm;
        if (c + 1 < C_) {       // issue next coil's loads before the FFT
            const float2* nB = bB + (size_t)(c + 1) * A_ * 131072;
            n0 = ((const float4*)nB)[t];
            n1 = ((const float4*)nB)[t + 128];
            nm = ((const float4*)(mT + (size_t)(c + 1) * 65536))[t];
        }
        fft512<1>(Are, Aim, Bre, Bim, tab, t);
        int p0 = P(128 + 2 * t), p1 = P(129 + 2 * t);   // crop y5 in [128,384)
        float v0x = Bre[p0], v0y = Bim[p0];
        float v1x = Bre[p1], v1y = Bim[p1];
        // acc += v * conj(m)
        ar0 += v0x * cm.x + v0y * cm.y;  ai0 += v0y * cm.x - v0x * cm.y;
        ar1 += v1x * cm.z + v1y * cm.w;  ai1 += v1y * cm.z - v1x * cm.w;
        c0 = n0; c1 = n1; cm = nm;
    }
    // planar out: Re plane [5][256][256] then Im plane; y = 2t, 2t+1
    size_t r0 = (size_t)a * 65536 + (size_t)(2 * t) * 256 + xcol;
    size_t r1 = r0 + 256;
    size_t i0 = 327680 + r0, i1 = 327680 + r1;
    if (r0 < (size_t)outFloats) out[r0] = ar0;
    if (r1 < (size_t)outFloats) out[r1] = ar1;
    if (i0 < (size_t)outFloats) out[i0] = ai0;
    if (i1 < (size_t)outFloats) out[i1] = ai1;
}

// ---------------------------------------------------------------------------
extern "C" void kernel_launch(void* const* d_in, const int* in_sizes, int n_in,
                              void* d_out, int out_size, void* d_ws, size_t ws_size,
                              hipStream_t stream) {
    const float* xr = (const float*)d_in[0];
    const float* xi = (const float*)d_in[1];
    const float* mr = (const float*)d_in[2];
    const float* mi = (const float*)d_in[3];
    const float* kr = (const float*)d_in[4];
    const float* ki = (const float*)d_in[5];
    float* out = (float*)d_out;
    (void)d_ws; (void)ws_size; (void)n_in; (void)in_sizes;

    k_inT   <<<dim3(8, 8, 17), dim3(32, 8), 0, stream>>>(xr, xi, mr, mi);
    k_fft1c <<<RPG * 256, 128, 0, stream>>>();
    k_colfmc<<<C_ * 512, 128, 0, stream>>>(kr, ki);
    k_outfr <<<A_ * 256, 128, 0, stream>>>(out, out_size);
}